// Round 1
// 722.923 us; speedup vs baseline: 1.0071x; 1.0071x over previous
//
#include <hip/hip_runtime.h>
#include <hip/hip_bf16.h>
#include <math.h>

// Problem constants (fixed by the reference):
//   T=131072 tokens, H=768, S=16384 spans, MAX_LEN=32, K1=3H=2304
#define H_DIM   768
#define S_SPAN  16384
#define K1_DIM  2304

typedef __attribute__((ext_vector_type(8))) short short8;   // 8 bf16 in 4 VGPRs
typedef __attribute__((ext_vector_type(4))) float floatx4;  // MFMA accumulator

__device__ __forceinline__ float gelu_exact(float x) {
    return 0.5f * x * (1.0f + erff(x * 0.70710678118654752f));
}

// Async global->LDS, 16 B per lane. LDS dest is wave-uniform base + lane*16.
__device__ __forceinline__ void async_ld16(const __hip_bfloat16* g, __hip_bfloat16* l) {
    __builtin_amdgcn_global_load_lds(
        (const __attribute__((address_space(1))) void*)g,
        (__attribute__((address_space(3))) void*)l, 16, 0, 0);
}

__device__ __forceinline__ void store_out(float* p, float v) { *p = v; }
__device__ __forceinline__ void store_out(__hip_bfloat16* p, float v) { *p = __float2bfloat16(v); }

// ---------------------------------------------------------------------------
// Kernel 1: fp32 (K x N) -> bf16 (N x K) transpose-convert (for W1, W2).
// 32x32 LDS tile, padded. Grid: (N/32, K/32), block (32,8).
// ---------------------------------------------------------------------------
__global__ void transpose_to_bf16(const float* __restrict__ src,     // K x N
                                  __hip_bfloat16* __restrict__ dst,  // N x K
                                  int K, int N) {
    __shared__ float tile[32][33];
    const int nb = blockIdx.x * 32;
    const int kb = blockIdx.y * 32;
    const int tx = threadIdx.x;   // 0..31
    const int ty = threadIdx.y;   // 0..7
#pragma unroll
    for (int i = ty; i < 32; i += 8)
        tile[i][tx] = src[(size_t)(kb + i) * N + nb + tx];
    __syncthreads();
#pragma unroll
    for (int i = ty; i < 32; i += 8)
        dst[(size_t)(nb + i) * K + kb + tx] = __float2bfloat16(tile[tx][i]);
}

// ---------------------------------------------------------------------------
// Kernel 2: span gather -> feat bf16 (S x 2304) = [h_start | h_end | h_mean].
// REWRITE (this round): one WAVE per span, 4 spans per 256-thread block.
//  - lane owns 3 float4 slices of the 768-col row (slots lane, lane+64, lane+128)
//  - explicit 2-deep software pipeline: row i+1 loads issued while row i adds.
//    start <= T-33 and len <= 32  =>  row start+32 always in-bounds, so the
//    prefetch needs NO guard (zero divergence, always >=3 loads in flight).
//  - h_start stored immediately after row 0 (frees 12 VGPRs).
// NOTE: harness passes ALL integer inputs as int32, so spans is int32 pairs.
// ---------------------------------------------------------------------------
__device__ __forceinline__ void store_row3(__hip_bfloat16* f, int lane,
                                           float4 v0, float4 v1, float4 v2) {
    union { __hip_bfloat16 h[4]; uint2 u; } pk;
    pk.h[0] = __float2bfloat16(v0.x); pk.h[1] = __float2bfloat16(v0.y);
    pk.h[2] = __float2bfloat16(v0.z); pk.h[3] = __float2bfloat16(v0.w);
    *(uint2*)(f + 4 * lane) = pk.u;
    pk.h[0] = __float2bfloat16(v1.x); pk.h[1] = __float2bfloat16(v1.y);
    pk.h[2] = __float2bfloat16(v1.z); pk.h[3] = __float2bfloat16(v1.w);
    *(uint2*)(f + 4 * (lane + 64)) = pk.u;
    pk.h[0] = __float2bfloat16(v2.x); pk.h[1] = __float2bfloat16(v2.y);
    pk.h[2] = __float2bfloat16(v2.z); pk.h[3] = __float2bfloat16(v2.w);
    *(uint2*)(f + 4 * (lane + 128)) = pk.u;
}

__global__ __launch_bounds__(256)
void gather_feat(const float* __restrict__ emb,          // T x 768
                 const int* __restrict__ spans,          // S x 2 (int32!)
                 __hip_bfloat16* __restrict__ feat) {    // S x 2304
    const int s    = blockIdx.x * 4 + (threadIdx.x >> 6);
    const int lane = threadIdx.x & 63;
    const int st   = spans[2 * s];
    const int len  = spans[2 * s + 1] - st;

    const float4* r = (const float4*)(emb + (size_t)st * H_DIM);
    float4 a0 = r[lane], a1 = r[lane + 64], a2 = r[lane + 128];   // row 0

    __hip_bfloat16* f = feat + (size_t)s * K1_DIM;
    store_row3(f, lane, a0, a1, a2);                              // h_start now

    float4 s0 = a0, s1 = a1, s2 = a2;
    r += H_DIM / 4;
    float4 n0 = r[lane], n1 = r[lane + 64], n2 = r[lane + 128];   // row 1 (safe even if len==1)

    for (int i = 1; i < len; ++i) {
        a0 = n0; a1 = n1; a2 = n2;
        r += H_DIM / 4;
        n0 = r[lane]; n1 = r[lane + 64]; n2 = r[lane + 128];      // row i+1 (always in-bounds)
        s0.x += a0.x; s0.y += a0.y; s0.z += a0.z; s0.w += a0.w;
        s1.x += a1.x; s1.y += a1.y; s1.z += a1.z; s1.w += a1.w;
        s2.x += a2.x; s2.y += a2.y; s2.z += a2.z; s2.w += a2.w;
    }

    store_row3(f + H_DIM, lane, a0, a1, a2);                      // h_end (= row len-1)

    const float inv = 1.0f / (float)len;
    s0.x *= inv; s0.y *= inv; s0.z *= inv; s0.w *= inv;
    s1.x *= inv; s1.y *= inv; s1.z *= inv; s1.w *= inv;
    s2.x *= inv; s2.y *= inv; s2.z *= inv; s2.w *= inv;
    store_row3(f + 2 * H_DIM, lane, s0, s1, s2);                  // h_mean
}

// ---------------------------------------------------------------------------
// Kernel 3/4: C = gelu(A @ B + bias).  A: M x K bf16 row-major.
// Bt: N x K bf16 row-major (B transposed). C: M x N (bf16 or fp32).
// 128x128 tile, BK=32, 4 waves (2x2), each wave 4x4 of 16x16x32 MFMA.
// m97 structure: global_load_lds width-16 staging, 2-barrier K-loop.
// This round: + T1 XCD-aware block swizzle (nwg=768, %8==0 -> simple form
// is bijective). Groups all 6 N-tiles of an A row-panel on one XCD's L2.
// ---------------------------------------------------------------------------
template <typename OutT>
__global__ __launch_bounds__(256, 3)
void gemm_bias_gelu(const __hip_bfloat16* __restrict__ A,
                    const __hip_bfloat16* __restrict__ Bt,
                    const float* __restrict__ bias,
                    OutT* __restrict__ C,
                    int M, int N, int K) {
    __shared__ __align__(16) __hip_bfloat16 sA[128 * 32];
    __shared__ __align__(16) __hip_bfloat16 sB[128 * 32];

    const int tid  = threadIdx.x;
    const int wave = tid >> 6;
    const int lane = tid & 63;
    const int waveM = (wave >> 1) * 64;
    const int waveN = (wave & 1) * 64;

    // T1 XCD swizzle: nwg divisible by 8 for both GEMMs (6*128 = 768).
    const unsigned nbx = gridDim.x;
    unsigned lin = blockIdx.y * nbx + blockIdx.x;
    const unsigned chunk = (nbx * gridDim.y) >> 3;
    lin = (lin & 7) * chunk + (lin >> 3);
    const int tm0 = (int)(lin / nbx) * 128;
    const int tn0 = (int)(lin % nbx) * 128;

    const __hip_bfloat16* Abase = A + (size_t)tm0 * K;
    const __hip_bfloat16* Bbase = Bt + (size_t)tn0 * K;

    // Staging: each wave stages 32 rows of A and 32 rows of Bt per K-tile,
    // two global_load_lds insts each (16 rows x 64 B per inst; 4 lanes/row).
    const int srow = wave * 32 + (lane >> 2);
    const int skof = (lane & 3) * 8;
    const __hip_bfloat16* gA0 = Abase + (size_t)srow * K + skof;
    const __hip_bfloat16* gA1 = gA0 + (size_t)16 * K;
    const __hip_bfloat16* gB0 = Bbase + (size_t)srow * K + skof;
    const __hip_bfloat16* gB1 = gB0 + (size_t)16 * K;
    __hip_bfloat16* lA0 = &sA[wave * 1024];
    __hip_bfloat16* lA1 = &sA[wave * 1024 + 512];
    __hip_bfloat16* lB0 = &sB[wave * 1024];
    __hip_bfloat16* lB1 = &sB[wave * 1024 + 512];

    floatx4 acc[4][4] = {};

    const int fr = lane & 15;         // fragment row (A) / col (B) within 16
    const int fq = (lane >> 4) * 8;   // fragment k offset (quad * 8)

    for (int k0 = 0; k0 < K; k0 += 32) {
        __syncthreads();   // all waves done reading previous tile
        async_ld16(gA0 + k0, lA0);
        async_ld16(gA1 + k0, lA1);
        async_ld16(gB0 + k0, lB0);
        async_ld16(gB1 + k0, lB1);
        __syncthreads();   // drains vmcnt -> LDS tiles ready

        short8 af[4], bfr[4];
#pragma unroll
        for (int i = 0; i < 4; ++i) {
            af[i]  = *(const short8*)&sA[(waveM + i * 16 + fr) * 32 + fq];
            bfr[i] = *(const short8*)&sB[(waveN + i * 16 + fr) * 32 + fq];
        }
#pragma unroll
        for (int mi = 0; mi < 4; ++mi)
#pragma unroll
            for (int ni = 0; ni < 4; ++ni)
                acc[mi][ni] = __builtin_amdgcn_mfma_f32_16x16x32_bf16(
                    af[mi], bfr[ni], acc[mi][ni], 0, 0, 0);
    }

    // Epilogue: C/D layout col=lane&15, row=(lane>>4)*4+reg  [m89-verified]
    const int col = lane & 15;
    const int rq  = (lane >> 4) * 4;
#pragma unroll
    for (int ni = 0; ni < 4; ++ni) {
        const int gc = tn0 + waveN + ni * 16 + col;
        const float bv = bias[gc];
#pragma unroll
        for (int mi = 0; mi < 4; ++mi) {
#pragma unroll
            for (int r = 0; r < 4; ++r) {
                const int gr = tm0 + waveM + mi * 16 + rq + r;
                store_out(&C[(size_t)gr * N + gc], gelu_exact(acc[mi][ni][r] + bv));
            }
        }
    }
}

// ---------------------------------------------------------------------------
extern "C" void kernel_launch(void* const* d_in, const int* in_sizes, int n_in,
                              void* d_out, int out_size, void* d_ws, size_t ws_size,
                              hipStream_t stream) {
    const float* token_emb = (const float*)d_in[0];  // T x 768
    const int*   spans     = (const int*)d_in[1];    // S x 2 (int32 per harness)
    const float* W1        = (const float*)d_in[2];  // 2304 x 768
    const float* b1        = (const float*)d_in[3];  // 768
    const float* W2        = (const float*)d_in[4];  // 768 x 768
    const float* b2        = (const float*)d_in[5];  // 768
    float*       out       = (float*)d_out;          // S x 768

    // Workspace layout (bf16), total ~105.4 MB
    __hip_bfloat16* W1t  = (__hip_bfloat16*)d_ws;                  // 768 x 2304
    __hip_bfloat16* W2t  = W1t  + (size_t)H_DIM * K1_DIM;          // 768 x 768
    __hip_bfloat16* feat = W2t  + (size_t)H_DIM * H_DIM;           // S x 2304
    __hip_bfloat16* z    = feat + (size_t)S_SPAN * K1_DIM;         // S x 768

    transpose_to_bf16<<<dim3(H_DIM / 32, K1_DIM / 32), dim3(32, 8), 0, stream>>>(
        W1, W1t, K1_DIM, H_DIM);
    transpose_to_bf16<<<dim3(H_DIM / 32, H_DIM / 32), dim3(32, 8), 0, stream>>>(
        W2, W2t, H_DIM, H_DIM);
    gather_feat<<<S_SPAN / 4, 256, 0, stream>>>(token_emb, spans, feat);
    gemm_bias_gelu<__hip_bfloat16><<<dim3(H_DIM / 128, S_SPAN / 128), 256, 0, stream>>>(
        feat, W1t, b1, z, S_SPAN, H_DIM, K1_DIM);
    gemm_bias_gelu<float><<<dim3(H_DIM / 128, S_SPAN / 128), 256, 0, stream>>>(
        z, W2t, b2, out, S_SPAN, H_DIM, H_DIM);
}